// Round 6
// baseline (241.850 us; speedup 1.0000x reference)
//
#include <hip/hip_runtime.h>
#include <hip/hip_bf16.h>

#define AN 256
#define BN 64
#define DN 768
#define G1N 4
#define G2N 8
#define KI 24   // 768 / 32

typedef __attribute__((ext_vector_type(8))) short short8;   // 8 bf16
typedef __attribute__((ext_vector_type(4))) short bf16x4;   // 4 bf16
typedef __attribute__((ext_vector_type(4))) float floatx4;  // MFMA acc

static __device__ __forceinline__ unsigned short f2bf(float f) {
    union { float f; unsigned int u; } v; v.f = f;
    unsigned int r = v.u + 0x7FFF + ((v.u >> 16) & 1);  // RNE
    return (unsigned short)(r >> 16);
}
static __device__ __forceinline__ float bf2f(short s) {
    union { unsigned int u; float f; } v;
    v.u = ((unsigned int)(unsigned short)s) << 16;
    return v.f;
}

// ---------------------------------------------------------------------------
// k_u: u[a,l] = W2[g2(a)] @ Wh[a][:,l]  ->  Wcs[g2*512 + c][d] bf16
//      (c = bucket slot: 2*pos + l, pos = deterministic order within g2 group)
//      tile-0 blocks also emit bcu[g2*512+c] = b2[g2].Wh[a][:,l] + bh[a,l].
// grid (12 d-tiles, 8 g2-groups) x 256. No inter-kernel list dependency:
// each block rebuilds the bucket from g2i via LDS scan.
// ---------------------------------------------------------------------------
__global__ __launch_bounds__(256) void k_u(
    const float* __restrict__ W2, const float* __restrict__ Wh,
    const float* __restrict__ b2, const float* __restrict__ bh,
    const int* __restrict__ g2i,
    unsigned short* __restrict__ Wcs, float* __restrict__ bcu)
{
    const int g = blockIdx.y;
    const int tid = threadIdx.x;
    __shared__ int g2s[AN];
    __shared__ int lst[AN];
    g2s[tid] = g2i[tid];
    __syncthreads();
    int pos = 0;
    const int my = g2s[tid];
    for (int a2 = 0; a2 < tid; ++a2) pos += (g2s[a2] == my);
    const int n = __syncthreads_count(my == g);
    if (my == g) lst[pos] = tid;
    __syncthreads();
    const int cols = 2 * n;

    const int lane = tid & 63, wave = tid >> 6;
    const int nn = lane & 15, quad = lane >> 4;
    const int mbase = blockIdx.x * 64;
    const int m_row = mbase + wave * 16 + nn;

    // A = W2[g] rows (natural layout, k=e contiguous), fp32 -> bf16 regs
    const float* ap = W2 + ((size_t)g * DN + m_row) * DN + quad * 8;
    short8 Areg[KI];
    #pragma unroll
    for (int kk = 0; kk < KI; ++kk) {
        float4 a0 = *(const float4*)(ap + kk * 32);
        float4 a1 = *(const float4*)(ap + kk * 32 + 4);
        short8 af;
        af[0] = (short)f2bf(a0.x); af[1] = (short)f2bf(a0.y);
        af[2] = (short)f2bf(a0.z); af[3] = (short)f2bf(a0.w);
        af[4] = (short)f2bf(a1.x); af[5] = (short)f2bf(a1.y);
        af[6] = (short)f2bf(a1.z); af[7] = (short)f2bf(a1.w);
        Areg[kk] = af;
    }

    const bool biasw = (blockIdx.x == 0) && (wave == 0);

    for (int c0 = 0; c0 < cols; c0 += 16) {
        const int c = c0 + nn;
        const bool valid = (c < cols);
        const int cl = valid ? c : cols - 1;
        const int a = lst[cl >> 1], l = cl & 1;
        // Wh[a][e][l]: float idx = a*1536 + e*2 + l; lane covers e = kk*32+quad*8 .. +7
        const float* bp = Wh + (size_t)a * (DN * 2) + quad * 16;
        floatx4 acc = {0, 0, 0, 0};
        float sacc = 0.f;
        #pragma unroll
        for (int kk = 0; kk < KI; ++kk) {
            const float* bk = bp + kk * 64;
            float4 f0 = *(const float4*)(bk);
            float4 f1 = *(const float4*)(bk + 4);
            float4 f2v = *(const float4*)(bk + 8);
            float4 f3 = *(const float4*)(bk + 12);
            float v0 = l ? f0.y : f0.x,  v1 = l ? f0.w : f0.z;
            float v2 = l ? f1.y : f1.x,  v3 = l ? f1.w : f1.z;
            float v4 = l ? f2v.y : f2v.x, v5 = l ? f2v.w : f2v.z;
            float v6 = l ? f3.y : f3.x,  v7 = l ? f3.w : f3.z;
            short8 bf;
            bf[0] = (short)f2bf(v0); bf[1] = (short)f2bf(v1);
            bf[2] = (short)f2bf(v2); bf[3] = (short)f2bf(v3);
            bf[4] = (short)f2bf(v4); bf[5] = (short)f2bf(v5);
            bf[6] = (short)f2bf(v6); bf[7] = (short)f2bf(v7);
            if (biasw) {
                const float* b2p = b2 + (size_t)g * DN + kk * 32 + quad * 8;
                float4 c0v = *(const float4*)(b2p);
                float4 c1v = *(const float4*)(b2p + 4);
                sacc += v0 * c0v.x + v1 * c0v.y + v2 * c0v.z + v3 * c0v.w
                      + v4 * c1v.x + v5 * c1v.y + v6 * c1v.z + v7 * c1v.w;
            }
            acc = __builtin_amdgcn_mfma_f32_16x16x32_bf16(Areg[kk], bf, acc, 0, 0, 0);
        }
        if (valid) {
            const int dbase = mbase + wave * 16 + quad * 4;
            bf16x4 v;
            #pragma unroll
            for (int r = 0; r < 4; ++r) v[r] = (short)f2bf(acc[r]);
            *(bf16x4*)(Wcs + (size_t)(g * 512 + c) * DN + dbase) = v;
        }
        if (biasw) {
            sacc += __shfl_xor(sacc, 16, 64);
            sacc += __shfl_xor(sacc, 32, 64);
            if (quad == 0 && valid)
                bcu[g * 512 + c] = sacc + bh[a * 2 + l];
        }
    }
}

// ---------------------------------------------------------------------------
// k_v: v[a,l] = W1[g1(a)] @ u[a,l]  ->  Vs[g1*512 + j][d'] bf16
//      (j = slot in g1 bucket). tile-0 also emits sv[g1*512+j] = b1[g1].u + bcu.
// grid (12 d'-tiles, 4 g1-groups) x 256.
// ---------------------------------------------------------------------------
__global__ __launch_bounds__(256) void k_v(
    const float* __restrict__ W1, const float* __restrict__ b1,
    const unsigned short* __restrict__ Wcs, const float* __restrict__ bcu,
    const int* __restrict__ g1i, const int* __restrict__ g2i,
    unsigned short* __restrict__ Vs, float* __restrict__ sv)
{
    const int g = blockIdx.y;
    const int tid = threadIdx.x;
    __shared__ int g1s[AN], g2s[AN];
    __shared__ int lst[AN];
    __shared__ int rps[AN];   // u-row base for annotator a: g2*512 + 2*pos2
    g1s[tid] = g1i[tid];
    g2s[tid] = g2i[tid];
    __syncthreads();
    int p1 = 0, p2 = 0;
    const int m1 = g1s[tid], m2 = g2s[tid];
    for (int a2 = 0; a2 < tid; ++a2) {
        p1 += (g1s[a2] == m1);
        p2 += (g2s[a2] == m2);
    }
    rps[tid] = m2 * 512 + p2 * 2;
    const int n = __syncthreads_count(m1 == g);
    if (m1 == g) lst[p1] = tid;
    __syncthreads();
    const int cols = 2 * n;

    const int lane = tid & 63, wave = tid >> 6;
    const int nn = lane & 15, quad = lane >> 4;
    const int mbase = blockIdx.x * 64;
    const int m_row = mbase + wave * 16 + nn;

    // A = W1[g] rows (natural layout, k=d contiguous), fp32 -> bf16 regs
    const float* ap = W1 + ((size_t)g * DN + m_row) * DN + quad * 8;
    short8 Areg[KI];
    #pragma unroll
    for (int kk = 0; kk < KI; ++kk) {
        float4 a0 = *(const float4*)(ap + kk * 32);
        float4 a1 = *(const float4*)(ap + kk * 32 + 4);
        short8 af;
        af[0] = (short)f2bf(a0.x); af[1] = (short)f2bf(a0.y);
        af[2] = (short)f2bf(a0.z); af[3] = (short)f2bf(a0.w);
        af[4] = (short)f2bf(a1.x); af[5] = (short)f2bf(a1.y);
        af[6] = (short)f2bf(a1.z); af[7] = (short)f2bf(a1.w);
        Areg[kk] = af;
    }

    const bool biasw = (blockIdx.x == 0) && (wave == 0);

    for (int c0 = 0; c0 < cols; c0 += 16) {
        const int c = c0 + nn;
        const bool valid = (c < cols);
        const int cl = valid ? c : cols - 1;
        const int a = lst[cl >> 1], l = cl & 1;
        const int rp = rps[a] + l;
        const unsigned short* bp = Wcs + (size_t)rp * DN + quad * 8;
        floatx4 acc = {0, 0, 0, 0};
        float sacc = 0.f;
        #pragma unroll
        for (int kk = 0; kk < KI; ++kk) {
            short8 bf = *(const short8*)(bp + kk * 32);
            if (biasw) {
                const float* b1p = b1 + (size_t)g * DN + kk * 32 + quad * 8;
                float4 c0v = *(const float4*)(b1p);
                float4 c1v = *(const float4*)(b1p + 4);
                sacc += bf2f(bf[0]) * c0v.x + bf2f(bf[1]) * c0v.y
                      + bf2f(bf[2]) * c0v.z + bf2f(bf[3]) * c0v.w
                      + bf2f(bf[4]) * c1v.x + bf2f(bf[5]) * c1v.y
                      + bf2f(bf[6]) * c1v.z + bf2f(bf[7]) * c1v.w;
            }
            acc = __builtin_amdgcn_mfma_f32_16x16x32_bf16(Areg[kk], bf, acc, 0, 0, 0);
        }
        if (valid) {
            const int dbase = mbase + wave * 16 + quad * 4;
            bf16x4 v;
            #pragma unroll
            for (int r = 0; r < 4; ++r) v[r] = (short)f2bf(acc[r]);
            *(bf16x4*)(Vs + (size_t)(g * 512 + c) * DN + dbase) = v;
        }
        if (biasw) {
            sacc += __shfl_xor(sacc, 16, 64);
            sacc += __shfl_xor(sacc, 32, 64);
            if (quad == 0 && valid)
                sv[g * 512 + c] = sacc + bcu[rp];
        }
    }
}

// ---------------------------------------------------------------------------
// k_out: out[b, a, l] = pooled[b,:] . Vs[g1*512+j][:] + sv[g1*512+j]
// grid (32 col-tiles, 4 g1-groups) x 256; 16 columns/block, m=batch split by wave.
// ---------------------------------------------------------------------------
__global__ __launch_bounds__(256) void k_out(
    const float* __restrict__ pooled, const unsigned short* __restrict__ Vs,
    const float* __restrict__ sv, const int* __restrict__ g1i,
    float* __restrict__ out)
{
    const int g = blockIdx.y;
    const int tid = threadIdx.x;
    __shared__ int g1s[AN];
    __shared__ int lst[AN];
    g1s[tid] = g1i[tid];
    __syncthreads();
    int p1 = 0;
    const int m1 = g1s[tid];
    for (int a2 = 0; a2 < tid; ++a2) p1 += (g1s[a2] == m1);
    const int n = __syncthreads_count(m1 == g);
    if (m1 == g) lst[p1] = tid;
    __syncthreads();
    const int cols = 2 * n;
    const int nt0 = blockIdx.x * 16;
    if (nt0 >= cols) return;

    const int lane = tid & 63, wave = tid >> 6;
    const int nn = lane & 15, quad = lane >> 4;

    const int c = nt0 + nn;
    const bool valid = (c < cols);
    const int cl = valid ? c : cols - 1;
    const int a = lst[cl >> 1], l = cl & 1;

    const float* ap = pooled + (size_t)(wave * 16 + nn) * DN + quad * 8;
    const unsigned short* bp = Vs + (size_t)(g * 512 + cl) * DN + quad * 8;

    floatx4 acc = {0, 0, 0, 0};
    #pragma unroll
    for (int kk = 0; kk < KI; ++kk) {
        float4 a0 = *(const float4*)(ap + kk * 32);
        float4 a1 = *(const float4*)(ap + kk * 32 + 4);
        short8 af;
        af[0] = (short)f2bf(a0.x); af[1] = (short)f2bf(a0.y);
        af[2] = (short)f2bf(a0.z); af[3] = (short)f2bf(a0.w);
        af[4] = (short)f2bf(a1.x); af[5] = (short)f2bf(a1.y);
        af[6] = (short)f2bf(a1.z); af[7] = (short)f2bf(a1.w);
        short8 bf = *(const short8*)(bp + kk * 32);
        acc = __builtin_amdgcn_mfma_f32_16x16x32_bf16(af, bf, acc, 0, 0, 0);
    }
    if (valid) {
        const float bv = sv[g * 512 + cl];
        #pragma unroll
        for (int r = 0; r < 4; ++r)
            out[(size_t)(wave * 16 + quad * 4 + r) * (AN * 2) + a * 2 + l] = acc[r] + bv;
    }
}

extern "C" void kernel_launch(void* const* d_in, const int* in_sizes, int n_in,
                              void* d_out, int out_size, void* d_ws, size_t ws_size,
                              hipStream_t stream) {
    const float* pooled = (const float*)d_in[0];
    const float* W1     = (const float*)d_in[1];
    const float* b1     = (const float*)d_in[2];
    const float* W2     = (const float*)d_in[3];
    const float* b2     = (const float*)d_in[4];
    const float* Wh     = (const float*)d_in[5];
    const float* bh     = (const float*)d_in[6];
    const int*   g1i    = (const int*)d_in[7];
    const int*   g2i    = (const int*)d_in[8];
    float* out = (float*)d_out;

    // Workspace carve (~9.5 MB): bcu | sv | Wcs | Vs
    char* ws = (char*)d_ws;
    float* bcu = (float*)ws;                         ws += (size_t)G2N * 512 * 4;
    float* sv  = (float*)ws;                         ws += (size_t)G1N * 512 * 4;
    unsigned short* Wcs = (unsigned short*)ws;       ws += (size_t)G2N * 512 * DN * 2;
    unsigned short* Vs  = (unsigned short*)ws;       ws += (size_t)G1N * 512 * DN * 2;

    dim3 blk(256);
    k_u  <<<dim3(12, G2N), blk, 0, stream>>>(W2, Wh, b2, bh, g2i, Wcs, bcu);
    k_v  <<<dim3(12, G1N), blk, 0, stream>>>(W1, b1, Wcs, bcu, g1i, g2i, Vs, sv);
    k_out<<<dim3(32, G1N), blk, 0, stream>>>(pooled, Vs, sv, g1i, out);
}

// Round 7
// 159.882 us; speedup vs baseline: 1.5127x; 1.5127x over previous
//
#include <hip/hip_runtime.h>
#include <hip/hip_bf16.h>

#define AN 256
#define BN 64
#define DN 768
#define G1N 4
#define G2N 8
#define KI 24   // 768 / 32

typedef __attribute__((ext_vector_type(8))) short short8;   // 8 bf16
typedef __attribute__((ext_vector_type(4))) float floatx4;  // MFMA acc

static __device__ __forceinline__ unsigned short f2bf(float f) {
    union { float f; unsigned int u; } v; v.f = f;
    unsigned int r = v.u + 0x7FFF + ((v.u >> 16) & 1);  // RNE
    return (unsigned short)(r >> 16);
}
static __device__ __forceinline__ float bf2f(short s) {
    union { unsigned int u; float f; } v;
    v.u = ((unsigned int)(unsigned short)s) << 16;
    return v.f;
}

// ---------------------------------------------------------------------------
// k_cvt: one-shot, massively parallel prep. grid = 3712 x 256.
//   bx <  1152 : W1 -> bf16 (2048 elems/block)
//   bx <  3456 : W2 -> bf16
//   else       : a = bx-3456: pack Wh[a] -> Whp[g2*512 + 2*s + l][e] bf16,
//                colmap[g2*512+2s+l] = a, s2idx[a] = s  (s = slot in g2 bucket)
// ---------------------------------------------------------------------------
__global__ __launch_bounds__(256) void k_cvt(
    const float* __restrict__ W1, const float* __restrict__ W2,
    const float* __restrict__ Wh, const int* __restrict__ g2i,
    unsigned short* __restrict__ W1b, unsigned short* __restrict__ W2b,
    unsigned short* __restrict__ Whp, int* __restrict__ colmap,
    int* __restrict__ s2idx)
{
    const int tid = threadIdx.x, bx = blockIdx.x;

    if (bx < 3456) {
        const float* src = (bx < 1152) ? W1 : W2;
        unsigned short* dst = (bx < 1152) ? W1b : W2b;
        const size_t i0 = ((size_t)(bx < 1152 ? bx : bx - 1152)) * 2048 + (size_t)tid * 8;
        float4 f0 = *(const float4*)(src + i0);
        float4 f1 = *(const float4*)(src + i0 + 4);
        short8 s;
        s[0] = (short)f2bf(f0.x); s[1] = (short)f2bf(f0.y);
        s[2] = (short)f2bf(f0.z); s[3] = (short)f2bf(f0.w);
        s[4] = (short)f2bf(f1.x); s[5] = (short)f2bf(f1.y);
        s[6] = (short)f2bf(f1.z); s[7] = (short)f2bf(f1.w);
        *(short8*)(dst + i0) = s;
        return;
    }

    // ---- Wh pack ----
    const int a = bx - 3456;
    __shared__ int g2s[AN];
    __shared__ int ss;
    g2s[tid] = g2i[tid];
    __syncthreads();
    if (tid == 0) {
        int my = g2s[a], s = 0;
        for (int j = 0; j < a; ++j) s += (g2s[j] == my);
        ss = s;
        s2idx[a] = s;
        colmap[my * 512 + 2 * s]     = a;
        colmap[my * 512 + 2 * s + 1] = a;
    }
    __syncthreads();
    const int my = g2s[a], s = ss;
    const size_t r0 = (size_t)my * 512 + 2 * s;
    const float* wa = Wh + (size_t)a * (DN * 2);
    #pragma unroll
    for (int i = 0; i < 3; ++i) {
        int e = i * 256 + tid;
        float2 v = *(const float2*)(wa + e * 2);
        Whp[r0 * DN + e]       = f2bf(v.x);
        Whp[(r0 + 1) * DN + e] = f2bf(v.y);
    }
}

// ---------------------------------------------------------------------------
// k_u: Wcs[g*512 + c][d] = sum_e W2b[g][d][e] * Whp[g*512+c][e]
// Flipped operands: A = Whp columns (m=c), B = W2b rows (n=d). All short8.
// grid (3 d-blocks, 8 col-chunks, 8 groups) x 256; wave owns 64 d (4 n-tiles).
// blockIdx.x==0/wave0 also emits bcu[c] = b2[g].Wh_col + bh.
// ---------------------------------------------------------------------------
__global__ __launch_bounds__(256) void k_u(
    const unsigned short* __restrict__ W2b, const unsigned short* __restrict__ Whp,
    const float* __restrict__ b2, const float* __restrict__ bh,
    const int* __restrict__ g2i, const int* __restrict__ colmap,
    unsigned short* __restrict__ Wcs, float* __restrict__ bcu)
{
    const int g = blockIdx.z;
    const int tid = threadIdx.x;
    const int n = __syncthreads_count(g2i[tid] == g);
    const int cols = 2 * n;
    const int nct = (cols + 15) >> 4;

    const int lane = tid & 63, wave = tid >> 6;
    const int nn = lane & 15, quad = lane >> 4;
    const int dbase = blockIdx.x * 256 + wave * 64;
    const bool biasw = (blockIdx.x == 0) && (wave == 0);

    const unsigned short* bp = W2b + ((size_t)g * DN + dbase + nn) * DN + quad * 8;

    for (int ct = blockIdx.y; ct < nct; ct += 8) {
        const unsigned short* ap = Whp + ((size_t)g * 512 + ct * 16 + nn) * DN + quad * 8;
        floatx4 acc[4] = {{0,0,0,0},{0,0,0,0},{0,0,0,0},{0,0,0,0}};
        float sacc = 0.f;
        #pragma unroll
        for (int kk = 0; kk < KI; ++kk) {
            short8 af = *(const short8*)(ap + kk * 32);
            if (biasw) {
                const float* b2p = b2 + (size_t)g * DN + kk * 32 + quad * 8;
                float4 c0v = *(const float4*)(b2p);
                float4 c1v = *(const float4*)(b2p + 4);
                sacc += bf2f(af[0]) * c0v.x + bf2f(af[1]) * c0v.y
                      + bf2f(af[2]) * c0v.z + bf2f(af[3]) * c0v.w
                      + bf2f(af[4]) * c1v.x + bf2f(af[5]) * c1v.y
                      + bf2f(af[6]) * c1v.z + bf2f(af[7]) * c1v.w;
            }
            #pragma unroll
            for (int nt = 0; nt < 4; ++nt) {
                short8 bf = *(const short8*)(bp + (size_t)(nt * 16) * DN + kk * 32);
                acc[nt] = __builtin_amdgcn_mfma_f32_16x16x32_bf16(af, bf, acc[nt], 0, 0, 0);
            }
        }
        #pragma unroll
        for (int nt = 0; nt < 4; ++nt)
            #pragma unroll
            for (int r = 0; r < 4; ++r) {
                int c = ct * 16 + quad * 4 + r;
                if (c < cols)
                    Wcs[((size_t)g * 512 + c) * DN + dbase + nt * 16 + nn] = f2bf(acc[nt][r]);
            }
        if (biasw) {
            sacc += __shfl_xor(sacc, 16, 64);
            sacc += __shfl_xor(sacc, 32, 64);
            int c = ct * 16 + nn;
            if (quad == 0 && c < cols) {
                int a = colmap[g * 512 + c];
                bcu[g * 512 + c] = sacc + bh[a * 2 + (c & 1)];
            }
        }
    }
}

// ---------------------------------------------------------------------------
// k_v: Vs[g*512 + c][d'] = sum_d W1b[g][d'][d] * Wcs[rp(c)][d]
// A = Wcs columns (one LDS-indexed row lookup per col-tile), B = W1b rows.
// grid (3 d'-blocks, 8 col-chunks, 4 groups) x 256.
// blockIdx.x==0/wave0 also emits sv[c] = b1[g].u_col + bcu[rp].
// ---------------------------------------------------------------------------
__global__ __launch_bounds__(256) void k_v(
    const unsigned short* __restrict__ W1b, const unsigned short* __restrict__ Wcs,
    const float* __restrict__ b1, const float* __restrict__ bcu,
    const int* __restrict__ g1i, const int* __restrict__ g2i,
    const int* __restrict__ s2idx,
    unsigned short* __restrict__ Vs, float* __restrict__ sv)
{
    const int g = blockIdx.z;
    const int tid = threadIdx.x;
    __shared__ int g1s[AN];
    __shared__ int lst[AN];
    __shared__ int rpa[AN];
    g1s[tid] = g1i[tid];
    rpa[tid] = g2i[tid] * 512 + 2 * s2idx[tid];
    __syncthreads();
    int p1 = 0;
    const int m1 = g1s[tid];
    for (int a2 = 0; a2 < tid; ++a2) p1 += (g1s[a2] == m1);
    const int n = __syncthreads_count(m1 == g);
    if (m1 == g) lst[p1] = tid;
    __syncthreads();
    const int cols = 2 * n;
    const int nct = (cols + 15) >> 4;

    const int lane = tid & 63, wave = tid >> 6;
    const int nn = lane & 15, quad = lane >> 4;
    const int dbase = blockIdx.x * 256 + wave * 64;
    const bool biasw = (blockIdx.x == 0) && (wave == 0);

    const unsigned short* bp = W1b + ((size_t)g * DN + dbase + nn) * DN + quad * 8;

    for (int ct = blockIdx.y; ct < nct; ct += 8) {
        const int c = ct * 16 + nn;
        const int cl = (c < cols) ? c : cols - 1;
        const int a = lst[cl >> 1];
        const int rp = rpa[a] + (cl & 1);
        const unsigned short* ap = Wcs + (size_t)rp * DN + quad * 8;
        floatx4 acc[4] = {{0,0,0,0},{0,0,0,0},{0,0,0,0},{0,0,0,0}};
        float sacc = 0.f;
        #pragma unroll
        for (int kk = 0; kk < KI; ++kk) {
            short8 af = *(const short8*)(ap + kk * 32);
            if (biasw) {
                const float* b1p = b1 + (size_t)g * DN + kk * 32 + quad * 8;
                float4 c0v = *(const float4*)(b1p);
                float4 c1v = *(const float4*)(b1p + 4);
                sacc += bf2f(af[0]) * c0v.x + bf2f(af[1]) * c0v.y
                      + bf2f(af[2]) * c0v.z + bf2f(af[3]) * c0v.w
                      + bf2f(af[4]) * c1v.x + bf2f(af[5]) * c1v.y
                      + bf2f(af[6]) * c1v.z + bf2f(af[7]) * c1v.w;
            }
            #pragma unroll
            for (int nt = 0; nt < 4; ++nt) {
                short8 bf = *(const short8*)(bp + (size_t)(nt * 16) * DN + kk * 32);
                acc[nt] = __builtin_amdgcn_mfma_f32_16x16x32_bf16(af, bf, acc[nt], 0, 0, 0);
            }
        }
        #pragma unroll
        for (int nt = 0; nt < 4; ++nt)
            #pragma unroll
            for (int r = 0; r < 4; ++r) {
                int cc = ct * 16 + quad * 4 + r;
                if (cc < cols)
                    Vs[((size_t)g * 512 + cc) * DN + dbase + nt * 16 + nn] = f2bf(acc[nt][r]);
            }
        if (biasw) {
            sacc += __shfl_xor(sacc, 16, 64);
            sacc += __shfl_xor(sacc, 32, 64);
            if (quad == 0 && c < cols)
                sv[g * 512 + c] = sacc + bcu[rp];
        }
    }
}

// ---------------------------------------------------------------------------
// k_out: out[b, a, l] = pooled[b,:] . Vs[g1*512+j][:] + sv[g1*512+j]
// grid (32 col-tiles, 4 g1-groups) x 256. (verified in rounds 5-6)
// ---------------------------------------------------------------------------
__global__ __launch_bounds__(256) void k_out(
    const float* __restrict__ pooled, const unsigned short* __restrict__ Vs,
    const float* __restrict__ sv, const int* __restrict__ g1i,
    float* __restrict__ out)
{
    const int g = blockIdx.y;
    const int tid = threadIdx.x;
    __shared__ int g1s[AN];
    __shared__ int lst[AN];
    g1s[tid] = g1i[tid];
    __syncthreads();
    int p1 = 0;
    const int m1 = g1s[tid];
    for (int a2 = 0; a2 < tid; ++a2) p1 += (g1s[a2] == m1);
    const int n = __syncthreads_count(m1 == g);
    if (m1 == g) lst[p1] = tid;
    __syncthreads();
    const int cols = 2 * n;
    const int nt0 = blockIdx.x * 16;
    if (nt0 >= cols) return;

    const int lane = tid & 63, wave = tid >> 6;
    const int nn = lane & 15, quad = lane >> 4;

    const int c = nt0 + nn;
    const bool valid = (c < cols);
    const int cl = valid ? c : cols - 1;
    const int a = lst[cl >> 1], l = cl & 1;

    const float* ap = pooled + (size_t)(wave * 16 + nn) * DN + quad * 8;
    const unsigned short* bp = Vs + (size_t)(g * 512 + cl) * DN + quad * 8;

    floatx4 acc = {0, 0, 0, 0};
    #pragma unroll
    for (int kk = 0; kk < KI; ++kk) {
        float4 a0 = *(const float4*)(ap + kk * 32);
        float4 a1 = *(const float4*)(ap + kk * 32 + 4);
        short8 af;
        af[0] = (short)f2bf(a0.x); af[1] = (short)f2bf(a0.y);
        af[2] = (short)f2bf(a0.z); af[3] = (short)f2bf(a0.w);
        af[4] = (short)f2bf(a1.x); af[5] = (short)f2bf(a1.y);
        af[6] = (short)f2bf(a1.z); af[7] = (short)f2bf(a1.w);
        short8 bf = *(const short8*)(bp + kk * 32);
        acc = __builtin_amdgcn_mfma_f32_16x16x32_bf16(af, bf, acc, 0, 0, 0);
    }
    if (valid) {
        const float bv = sv[g * 512 + cl];
        #pragma unroll
        for (int r = 0; r < 4; ++r)
            out[(size_t)(wave * 16 + quad * 4 + r) * (AN * 2) + a * 2 + l] = acc[r] + bv;
    }
}

extern "C" void kernel_launch(void* const* d_in, const int* in_sizes, int n_in,
                              void* d_out, int out_size, void* d_ws, size_t ws_size,
                              hipStream_t stream) {
    const float* pooled = (const float*)d_in[0];
    const float* W1     = (const float*)d_in[1];
    const float* b1     = (const float*)d_in[2];
    const float* W2     = (const float*)d_in[3];
    const float* b2     = (const float*)d_in[4];
    const float* Wh     = (const float*)d_in[5];
    const float* bh     = (const float*)d_in[6];
    const int*   g1i    = (const int*)d_in[7];
    const int*   g2i    = (const int*)d_in[8];
    float* out = (float*)d_out;

    // Workspace carve (~30 MB): bcu | sv | colmap | s2idx | W1b | W2b | Whp | Wcs | Vs
    char* ws = (char*)d_ws;
    float* bcu   = (float*)ws;                     ws += (size_t)G2N * 512 * 4;
    float* sv    = (float*)ws;                     ws += (size_t)G1N * 512 * 4;
    int*   colmap= (int*)ws;                       ws += (size_t)G2N * 512 * 4;
    int*   s2idx = (int*)ws;                       ws += (size_t)AN * 4;
    unsigned short* W1b = (unsigned short*)ws;     ws += (size_t)G1N * DN * DN * 2;
    unsigned short* W2b = (unsigned short*)ws;     ws += (size_t)G2N * DN * DN * 2;
    unsigned short* Whp = (unsigned short*)ws;     ws += (size_t)G2N * 512 * DN * 2;
    unsigned short* Wcs = (unsigned short*)ws;     ws += (size_t)G2N * 512 * DN * 2;
    unsigned short* Vs  = (unsigned short*)ws;     ws += (size_t)G1N * 512 * DN * 2;

    dim3 blk(256);
    k_cvt<<<dim3(3712),      blk, 0, stream>>>(W1, W2, Wh, g2i, W1b, W2b, Whp, colmap, s2idx);
    k_u  <<<dim3(3, 8, G2N), blk, 0, stream>>>(W2b, Whp, b2, bh, g2i, colmap, Wcs, bcu);
    k_v  <<<dim3(3, 8, G1N), blk, 0, stream>>>(W1b, Wcs, b1, bcu, g1i, g2i, s2idx, Vs, sv);
    k_out<<<dim3(32, G1N),   blk, 0, stream>>>(pooled, Vs, sv, g1i, out);
}

// Round 8
// 138.088 us; speedup vs baseline: 1.7514x; 1.1578x over previous
//
#include <hip/hip_runtime.h>
#include <hip/hip_bf16.h>

#define AN 256
#define BN 64
#define DN 768
#define G1N 4
#define G2N 8
#define KI 24            // 768 / 32
#define LPAD 776         // LDS row stride in shorts (768 + 8: 2-way max aliasing)

typedef __attribute__((ext_vector_type(8))) short short8;   // 8 bf16
typedef __attribute__((ext_vector_type(4))) short bf16x4;   // 4 bf16
typedef __attribute__((ext_vector_type(4))) float floatx4;  // MFMA acc

static __device__ __forceinline__ unsigned short f2bf(float f) {
    union { float f; unsigned int u; } v; v.f = f;
    unsigned int r = v.u + 0x7FFF + ((v.u >> 16) & 1);  // RNE
    return (unsigned short)(r >> 16);
}
static __device__ __forceinline__ float bf2f(short s) {
    union { unsigned int u; float f; } v;
    v.u = ((unsigned int)(unsigned short)s) << 16;
    return v.f;
}

// ---------------------------------------------------------------------------
// k_pack: grid = 256 x 256. Block a: pack Wh[a] -> Whp[g2*512 + 2s + l][e]
// (bf16, s = deterministic slot of a in its g2 bucket), s2idx[a] = s, and
// bcu[g2*512+2s+l] = b2[g2] . Wh[a][:,l] + bh[a,l].
// ---------------------------------------------------------------------------
__global__ __launch_bounds__(256) void k_pack(
    const float* __restrict__ Wh, const float* __restrict__ b2,
    const float* __restrict__ bh, const int* __restrict__ g2i,
    unsigned short* __restrict__ Whp, float* __restrict__ bcu,
    int* __restrict__ s2idx)
{
    const int tid = threadIdx.x, a = blockIdx.x;
    __shared__ int g2s[AN];
    __shared__ int ss;
    g2s[tid] = g2i[tid];
    __syncthreads();
    if (tid == 0) {
        int my = g2s[a], s = 0;
        for (int j = 0; j < a; ++j) s += (g2s[j] == my);
        ss = s;
        s2idx[a] = s;
    }
    __syncthreads();
    const int my = g2s[a], s = ss;
    const size_t r0 = (size_t)my * 512 + 2 * s;
    const float* wa = Wh + (size_t)a * (DN * 2);

    #pragma unroll
    for (int i = 0; i < 3; ++i) {
        int e = i * 256 + tid;
        float2 v = *(const float2*)(wa + e * 2);
        Whp[r0 * DN + e]       = f2bf(v.x);
        Whp[(r0 + 1) * DN + e] = f2bf(v.y);
    }

    const int wave = tid >> 6, lane = tid & 63;
    if (wave < 2) {
        const int l = wave;
        const float* b2p = b2 + (size_t)my * DN;
        float sacc = 0.f;
        #pragma unroll
        for (int k = 0; k < 12; ++k) {
            int e = k * 64 + lane;
            sacc += wa[e * 2 + l] * b2p[e];
        }
        #pragma unroll
        for (int off = 1; off < 64; off <<= 1) sacc += __shfl_xor(sacc, off, 64);
        if (lane == 0) bcu[r0 + l] = sacc + bh[a * 2 + l];
    }
}

// ---------------------------------------------------------------------------
// k_u: Wcs[g*512 + c][d] = sum_e W2[g][d][e] * Whp[g*512+c][e]
// grid (48 d-tiles, 8 groups) x 256. Each block stages 16 rows of W2[g]
// fp32->bf16 into LDS (read once chip-wide), one barrier, then waves stride
// over column tiles: A = Whp columns (global bf16), B = LDS rows.
// ---------------------------------------------------------------------------
__global__ __launch_bounds__(256) void k_u(
    const float* __restrict__ W2, const unsigned short* __restrict__ Whp,
    const int* __restrict__ g2i, unsigned short* __restrict__ Wcs)
{
    const int g = blockIdx.y, d0 = blockIdx.x * 16;
    const int tid = threadIdx.x;
    const int n = __syncthreads_count(g2i[tid] == g);
    const int cols = 2 * n;
    const int nct = (cols + 15) >> 4;

    __shared__ unsigned short Bs[16 * LPAD];
    {
        const int srow = tid >> 4, t16 = tid & 15;
        const float* srcr = W2 + ((size_t)g * DN + d0 + srow) * DN;
        unsigned short* dstr = &Bs[srow * LPAD];
        #pragma unroll
        for (int i = 0; i < 12; ++i) {
            int col4 = (i * 16 + t16) * 4;
            float4 v = *(const float4*)(srcr + col4);
            bf16x4 b;
            b[0] = (short)f2bf(v.x); b[1] = (short)f2bf(v.y);
            b[2] = (short)f2bf(v.z); b[3] = (short)f2bf(v.w);
            *(bf16x4*)(dstr + col4) = b;
        }
    }
    __syncthreads();

    const int lane = tid & 63, wave = tid >> 6;
    const int nn = lane & 15, quad = lane >> 4;
    const unsigned short* bsp = &Bs[nn * LPAD + quad * 8];

    for (int ct = wave; ct < nct; ct += 4) {
        const int c = ct * 16 + nn;
        const int cl = (c < cols) ? c : cols - 1;
        const unsigned short* ap = Whp + ((size_t)g * 512 + cl) * DN + quad * 8;
        floatx4 acc = {0, 0, 0, 0};
        #pragma unroll
        for (int kk = 0; kk < KI; ++kk) {
            short8 af = *(const short8*)(ap + kk * 32);
            short8 bf = *(const short8*)(bsp + kk * 32);
            acc = __builtin_amdgcn_mfma_f32_16x16x32_bf16(af, bf, acc, 0, 0, 0);
        }
        #pragma unroll
        for (int r = 0; r < 4; ++r) {
            int cc = ct * 16 + quad * 4 + r;
            if (cc < cols)
                Wcs[((size_t)g * 512 + cc) * DN + d0 + nn] = f2bf(acc[r]);
        }
    }
}

// ---------------------------------------------------------------------------
// k_v: Vs[g*512 + c][d'] = sum_d W1[g][d'][d] * Wcs[rp(c)][d]
// Same structure as k_u; A rows come from Wcs via g1-bucket LUT.
// blockIdx.x==0 waves also emit sv[c] = b1[g] . u_col + bcu[rp].
// grid (48 d'-tiles, 4 groups) x 256.
// ---------------------------------------------------------------------------
__global__ __launch_bounds__(256) void k_v(
    const float* __restrict__ W1, const unsigned short* __restrict__ Wcs,
    const float* __restrict__ b1, const float* __restrict__ bcu,
    const int* __restrict__ g1i, const int* __restrict__ g2i,
    const int* __restrict__ s2idx,
    unsigned short* __restrict__ Vs, float* __restrict__ sv)
{
    const int g = blockIdx.y, d0 = blockIdx.x * 16;
    const int tid = threadIdx.x;
    __shared__ int g1s[AN];
    __shared__ int lst[AN];
    __shared__ int rpa[AN];
    g1s[tid] = g1i[tid];
    rpa[tid] = g2i[tid] * 512 + 2 * s2idx[tid];
    __syncthreads();
    int p1 = 0;
    const int m1 = g1s[tid];
    for (int a2 = 0; a2 < tid; ++a2) p1 += (g1s[a2] == m1);
    const int n = __syncthreads_count(m1 == g);
    if (m1 == g) lst[p1] = tid;
    const int cols = 2 * n;
    const int nct = (cols + 15) >> 4;

    __shared__ unsigned short Bs[16 * LPAD];
    {
        const int srow = tid >> 4, t16 = tid & 15;
        const float* srcr = W1 + ((size_t)g * DN + d0 + srow) * DN;
        unsigned short* dstr = &Bs[srow * LPAD];
        #pragma unroll
        for (int i = 0; i < 12; ++i) {
            int col4 = (i * 16 + t16) * 4;
            float4 v = *(const float4*)(srcr + col4);
            bf16x4 b;
            b[0] = (short)f2bf(v.x); b[1] = (short)f2bf(v.y);
            b[2] = (short)f2bf(v.z); b[3] = (short)f2bf(v.w);
            *(bf16x4*)(dstr + col4) = b;
        }
    }
    __syncthreads();

    const int lane = tid & 63, wave = tid >> 6;
    const int nn = lane & 15, quad = lane >> 4;
    const unsigned short* bsp = &Bs[nn * LPAD + quad * 8];
    const bool biasw = (blockIdx.x == 0);

    for (int ct = wave; ct < nct; ct += 4) {
        const int c = ct * 16 + nn;
        const int cl = (c < cols) ? c : cols - 1;
        const int a = lst[cl >> 1];
        const int rp = rpa[a] + (cl & 1);
        const unsigned short* ap = Wcs + (size_t)rp * DN + quad * 8;
        floatx4 acc = {0, 0, 0, 0};
        float sacc = 0.f;
        #pragma unroll
        for (int kk = 0; kk < KI; ++kk) {
            short8 af = *(const short8*)(ap + kk * 32);
            if (biasw) {
                const float* b1p = b1 + (size_t)g * DN + kk * 32 + quad * 8;
                float4 c0v = *(const float4*)(b1p);
                float4 c1v = *(const float4*)(b1p + 4);
                sacc += bf2f(af[0]) * c0v.x + bf2f(af[1]) * c0v.y
                      + bf2f(af[2]) * c0v.z + bf2f(af[3]) * c0v.w
                      + bf2f(af[4]) * c1v.x + bf2f(af[5]) * c1v.y
                      + bf2f(af[6]) * c1v.z + bf2f(af[7]) * c1v.w;
            }
            short8 bf = *(const short8*)(bsp + kk * 32);
            acc = __builtin_amdgcn_mfma_f32_16x16x32_bf16(af, bf, acc, 0, 0, 0);
        }
        #pragma unroll
        for (int r = 0; r < 4; ++r) {
            int cc = ct * 16 + quad * 4 + r;
            if (cc < cols)
                Vs[((size_t)g * 512 + cc) * DN + d0 + nn] = f2bf(acc[r]);
        }
        if (biasw) {
            sacc += __shfl_xor(sacc, 16, 64);
            sacc += __shfl_xor(sacc, 32, 64);
            if (quad == 0 && c < cols)
                sv[g * 512 + c] = sacc + bcu[rp];
        }
    }
}

// ---------------------------------------------------------------------------
// k_out: out[b, a, l] = pooled[b,:] . Vs[g1*512+j][:] + sv[g1*512+j]
// grid (32 col-tiles, 4 g1-groups) x 256.  (verified rounds 5-7)
// ---------------------------------------------------------------------------
__global__ __launch_bounds__(256) void k_out(
    const float* __restrict__ pooled, const unsigned short* __restrict__ Vs,
    const float* __restrict__ sv, const int* __restrict__ g1i,
    float* __restrict__ out)
{
    const int g = blockIdx.y;
    const int tid = threadIdx.x;
    __shared__ int g1s[AN];
    __shared__ int lst[AN];
    g1s[tid] = g1i[tid];
    __syncthreads();
    int p1 = 0;
    const int m1 = g1s[tid];
    for (int a2 = 0; a2 < tid; ++a2) p1 += (g1s[a2] == m1);
    const int n = __syncthreads_count(m1 == g);
    if (m1 == g) lst[p1] = tid;
    __syncthreads();
    const int cols = 2 * n;
    const int nt0 = blockIdx.x * 16;
    if (nt0 >= cols) return;

    const int lane = tid & 63, wave = tid >> 6;
    const int nn = lane & 15, quad = lane >> 4;

    const int c = nt0 + nn;
    const bool valid = (c < cols);
    const int cl = valid ? c : cols - 1;
    const int a = lst[cl >> 1], l = cl & 1;

    const float* ap = pooled + (size_t)(wave * 16 + nn) * DN + quad * 8;
    const unsigned short* bp = Vs + (size_t)(g * 512 + cl) * DN + quad * 8;

    floatx4 acc = {0, 0, 0, 0};
    #pragma unroll
    for (int kk = 0; kk < KI; ++kk) {
        float4 a0 = *(const float4*)(ap + kk * 32);
        float4 a1 = *(const float4*)(ap + kk * 32 + 4);
        short8 af;
        af[0] = (short)f2bf(a0.x); af[1] = (short)f2bf(a0.y);
        af[2] = (short)f2bf(a0.z); af[3] = (short)f2bf(a0.w);
        af[4] = (short)f2bf(a1.x); af[5] = (short)f2bf(a1.y);
        af[6] = (short)f2bf(a1.z); af[7] = (short)f2bf(a1.w);
        short8 bf = *(const short8*)(bp + kk * 32);
        acc = __builtin_amdgcn_mfma_f32_16x16x32_bf16(af, bf, acc, 0, 0, 0);
    }
    if (valid) {
        const float bv = sv[g * 512 + cl];
        #pragma unroll
        for (int r = 0; r < 4; ++r)
            out[(size_t)(wave * 16 + quad * 4 + r) * (AN * 2) + a * 2 + l] = acc[r] + bv;
    }
}

extern "C" void kernel_launch(void* const* d_in, const int* in_sizes, int n_in,
                              void* d_out, int out_size, void* d_ws, size_t ws_size,
                              hipStream_t stream) {
    const float* pooled = (const float*)d_in[0];
    const float* W1     = (const float*)d_in[1];
    const float* b1     = (const float*)d_in[2];
    const float* W2     = (const float*)d_in[3];
    const float* b2     = (const float*)d_in[4];
    const float* Wh     = (const float*)d_in[5];
    const float* bh     = (const float*)d_in[6];
    const int*   g1i    = (const int*)d_in[7];
    const int*   g2i    = (const int*)d_in[8];
    float* out = (float*)d_out;

    // Workspace carve (~15.8 MB): bcu | sv | s2idx | Whp | Wcs | Vs
    char* ws = (char*)d_ws;
    float* bcu   = (float*)ws;                  ws += (size_t)G2N * 512 * 4;
    float* sv    = (float*)ws;                  ws += (size_t)G1N * 512 * 4;
    int*   s2idx = (int*)ws;                    ws += (size_t)AN * 4;
    unsigned short* Whp = (unsigned short*)ws;  ws += (size_t)G2N * 512 * DN * 2;
    unsigned short* Wcs = (unsigned short*)ws;  ws += (size_t)G2N * 512 * DN * 2;
    unsigned short* Vs  = (unsigned short*)ws;  ws += (size_t)G1N * 512 * DN * 2;

    dim3 blk(256);
    k_pack<<<dim3(AN),        blk, 0, stream>>>(Wh, b2, bh, g2i, Whp, bcu, s2idx);
    k_u   <<<dim3(48, G2N),   blk, 0, stream>>>(W2, Whp, g2i, Wcs);
    k_v   <<<dim3(48, G1N),   blk, 0, stream>>>(W1, Wcs, b1, bcu, g1i, g2i, s2idx, Vs, sv);
    k_out <<<dim3(32, G1N),   blk, 0, stream>>>(pooled, Vs, sv, g1i, out);
}